// Round 4
// baseline (97.196 us; speedup 1.0000x reference)
//
#include <hip/hip_runtime.h>

// ---------------------------------------------------------------------------
// Compile-time Clebsch-Gordan / real Wigner-3j machinery (mirrors reference).
// ---------------------------------------------------------------------------
namespace cg {

constexpr double fact(int n) {
  double r = 1.0;
  for (int i = 2; i <= n; ++i) r *= (double)i;
  return r;
}

constexpr double csqrt(double x) {
  if (x <= 0.0) return 0.0;
  double g = x < 1.0 ? 1.0 : x;
  for (int i = 0; i < 80; ++i) g = 0.5 * (g + x / g);
  return g;
}

struct cplx { double re, im; };
constexpr cplx cmul(cplx a, cplx b) {
  return cplx{a.re * b.re - a.im * b.im, a.re * b.im + a.im * b.re};
}

// Racah formula, e3nn convention: <j1 m1 j2 m2 | j3 m3>
constexpr double su2_cg(int j1, int m1, int j2, int m2, int j3, int m3) {
  if (m3 != m1 + m2) return 0.0;
  int vmin = -j1 + j2 + m3;
  if (-j1 + m1 > vmin) vmin = -j1 + m1;
  if (0 > vmin) vmin = 0;
  int vmax = j2 + j3 + m1;
  if (j3 - j1 + j2 < vmax) vmax = j3 - j1 + j2;
  if (j3 + m3 < vmax) vmax = j3 + m3;
  const double C = csqrt((2.0 * j3 + 1.0)
      * fact(j3 + j1 - j2) * fact(j3 - j1 + j2) * fact(j1 + j2 - j3)
      * fact(j3 + m3) * fact(j3 - m3)
      / (fact(j1 + j2 + j3 + 1) * fact(j1 - m1) * fact(j1 + m1)
         * fact(j2 - m2) * fact(j2 + m2)));
  double S = 0.0;
  for (int v = vmin; v <= vmax; ++v) {
    const double sgn = ((v + j2 + m2) & 1) ? -1.0 : 1.0;
    S += sgn * (fact(j2 + j3 + m1 - v) * fact(j1 - m1 + v)
         / (fact(v) * fact(j3 - j1 + j2 - v) * fact(j3 + m3 - v)
            * fact(v + j1 - j2 - m3)));
  }
  return C * S;
}

template <int L> struct QMat { cplx q[2 * L + 1][2 * L + 1]; };

// real -> complex SH change of basis (e3nn convention), rows m', cols m
template <int L>
constexpr QMat<L> make_q() {
  QMat<L> Q{};
  const double s = 1.0 / csqrt(2.0);
  for (int m = -L; m < 0; ++m) {
    Q.q[L + m][L - m] = cplx{s, 0.0};
    Q.q[L + m][L + m] = cplx{0.0, -s};
  }
  Q.q[L][L] = cplx{1.0, 0.0};
  for (int m = 1; m <= L; ++m) {
    const double sg = (m & 1) ? -1.0 : 1.0;
    Q.q[L + m][L + m] = cplx{sg * s, 0.0};
    Q.q[L + m][L - m] = cplx{0.0, sg * s};
  }
  cplx p{1.0, 0.0};                        // (-i)^L prefactor
  for (int t = 0; t < L; ++t) p = cmul(p, cplx{0.0, -1.0});
  for (int r = 0; r < 2 * L + 1; ++r)
    for (int c = 0; c < 2 * L + 1; ++c)
      Q.q[r][c] = cmul(p, Q.q[r][c]);
  return Q;
}

template <int L, int L1, int L2>
struct W3 { float t[2 * L + 1][2 * L1 + 1][2 * L2 + 1]; };

// real-basis wigner3j(L, L1, L2) * sqrt(2L+1), exactly as the reference CG dict
template <int L, int L1, int L2>
constexpr W3<L, L1, L2> wigner() {
  const QMat<L>  Q1 = make_q<L>();
  const QMat<L1> Q2 = make_q<L1>();
  const QMat<L2> Q3 = make_q<L2>();
  double C[2 * L + 1][2 * L1 + 1][2 * L2 + 1] = {};
  for (int m1 = -L; m1 <= L; ++m1)
    for (int m2 = -L1; m2 <= L1; ++m2) {
      const int m3 = m1 + m2;
      if (m3 >= -L2 && m3 <= L2)
        C[L + m1][L1 + m2][L2 + m3] = su2_cg(L, m1, L1, m2, L2, m3);
    }
  const double scale = csqrt(2.0 * L + 1.0) / csqrt(2.0 * L2 + 1.0);
  W3<L, L1, L2> R{};
  for (int j = 0; j < 2 * L + 1; ++j)
    for (int l = 0; l < 2 * L1 + 1; ++l)
      for (int m = 0; m < 2 * L2 + 1; ++m) {
        cplx acc{0.0, 0.0};
        for (int i = 0; i < 2 * L + 1; ++i) {
          const cplx q1 = Q1.q[i][j];
          if (q1.re == 0.0 && q1.im == 0.0) continue;
          for (int k = 0; k < 2 * L1 + 1; ++k) {
            const cplx q2 = Q2.q[k][l];
            if (q2.re == 0.0 && q2.im == 0.0) continue;
            const cplx q12 = cmul(q1, q2);
            for (int n = 0; n < 2 * L2 + 1; ++n) {
              const double c = C[i][k][n];
              if (c == 0.0) continue;
              const cplx q3c{Q3.q[n][m].re, -Q3.q[n][m].im};  // conj
              const cplx term = cmul(q12, q3c);
              acc.re += term.re * c;
              acc.im += term.im * c;
            }
          }
        }
        R.t[j][l][m] = (float)(acc.re * scale);
      }
  return R;
}

constexpr W3<0, 1, 1> W011 = wigner<0, 1, 1>();
constexpr W3<1, 1, 1> W111 = wigner<1, 1, 1>();
constexpr W3<2, 1, 1> W211 = wigner<2, 1, 1>();
constexpr W3<0, 2, 2> W022 = wigner<0, 2, 2>();
constexpr W3<1, 2, 2> W122 = wigner<1, 2, 2>();
constexpr W3<2, 2, 2> W222 = wigner<2, 2, 2>();
constexpr W3<3, 2, 2> W322 = wigner<3, 2, 2>();
constexpr W3<4, 2, 2> W422 = wigner<4, 2, 2>();

}  // namespace cg

// ---------------------------------------------------------------------------
// Kernel
// ---------------------------------------------------------------------------

template <int L, int L1, int L2>
__device__ __forceinline__ void contract(const cg::W3<L, L1, L2>& W,
                                         const float (&p)[2 * L1 + 1][2 * L2 + 1],
                                         float* __restrict__ o) {
#pragma unroll
  for (int i = 0; i < 2 * L + 1; ++i) {
    float acc = 0.0f;
#pragma unroll
    for (int j = 0; j < 2 * L1 + 1; ++j)
#pragma unroll
      for (int k = 0; k < 2 * L2 + 1; ++k) {
        const float c = W.t[i][j][k];
        if (c != 0.0f) acc = __builtin_fmaf(c, p[j][k], acc);
      }
    o[i] = acc;
  }
}

// per-batch layouts (floats):
//  f1: [0,256) l=0 | [256,1024) l=1 | [1024,2304) l=2           (2304)
//  f2: [0,768) l=1 | [768,1536) l=1 | [1536,2816) l=2           (2816)
//  out: 0 p0 | 768 p1l0 | 1024 p1l1 | 1792 p1l2
//       | 3072 p2l0 | 3328 p2l1 | 4096 p2l2 | 5376 p2l3 | 7168 p2l4 | 9472
//
// One block per batch row. All 37 outputs are computed into registers, then
// the output row is staged through LDS in TWO contiguous chunks
// ([0,5376) and [5376,9472)) so the LDS footprint is 5376 floats = 21.5 KB
// -> 7 blocks/CU (28 waves/CU) instead of 4. All compute/scatter strides are
// odd => <=2-way bank aliasing (free on CDNA4). Global traffic is 100%
// float4-coalesced.
__global__ __launch_bounds__(256) void tp_kernel(
    const float* __restrict__ f1, const float* __restrict__ f2,
    float* __restrict__ out, int B) {
  __shared__ __align__(16) float lds[5376];  // 21504 B -> 7 blocks/CU
  const int b = blockIdx.x;
  if (b >= B) return;
  const int t = threadIdx.x;  // 0..255 (also the channel index in phase 2)

  // ---------------- phase 1: coalesced float4 stage-in ----------------
  // f1 = 576 float4 -> lds f4 [0,576); f2 = 704 float4 -> lds f4 [576,1280)
  {
    const float4* s1 = reinterpret_cast<const float4*>(f1 + (size_t)b * 2304);
    const float4* s2 = reinterpret_cast<const float4*>(f2 + (size_t)b * 2816);
    float4* l4 = reinterpret_cast<float4*>(lds);
#pragma unroll
    for (int k = 0; k < 2; ++k) l4[t + k * 256] = s1[t + k * 256];        // 0..511
    if (t < 64) l4[512 + t] = s1[512 + t];                                 // 512..575
#pragma unroll
    for (int k = 0; k < 2; ++k) l4[576 + t + k * 256] = s2[t + k * 256];   // 576..1087
    if (t < 192) l4[1088 + t] = s2[512 + t];                               // 1088..1279
  }
  __syncthreads();

  // ---------------- phase 2: per-channel compute (37 output regs) ------
  const int m = t;
  float r0[3];                       // pair 0
  float o0, o1[3], o2[5];            // pair 1
  float q0, q1[3], q2[5], q3[7], q4[9];  // pair 2
  {
    const float s = lds[m];
#pragma unroll
    for (int k = 0; k < 3; ++k) r0[k] = s * lds[2304 + m * 3 + k];
  }
  {
    float a[3], c[3];
#pragma unroll
    for (int j = 0; j < 3; ++j) a[j] = lds[256 + m * 3 + j];
#pragma unroll
    for (int k = 0; k < 3; ++k) c[k] = lds[2304 + 768 + m * 3 + k];
    float p[3][3];
#pragma unroll
    for (int j = 0; j < 3; ++j)
#pragma unroll
      for (int k = 0; k < 3; ++k) p[j][k] = a[j] * c[k];
    contract<0, 1, 1>(cg::W011, p, &o0);
    contract<1, 1, 1>(cg::W111, p, o1);
    contract<2, 1, 1>(cg::W211, p, o2);
  }
  {
    float a[5], c[5];
#pragma unroll
    for (int j = 0; j < 5; ++j) a[j] = lds[1024 + m * 5 + j];
#pragma unroll
    for (int k = 0; k < 5; ++k) c[k] = lds[2304 + 1536 + m * 5 + k];
    float p[5][5];
#pragma unroll
    for (int j = 0; j < 5; ++j)
#pragma unroll
      for (int k = 0; k < 5; ++k) p[j][k] = a[j] * c[k];
    contract<0, 2, 2>(cg::W022, p, &q0);
    contract<1, 2, 2>(cg::W122, p, q1);
    contract<2, 2, 2>(cg::W222, p, q2);
    contract<3, 2, 2>(cg::W322, p, q3);
    contract<4, 2, 2>(cg::W422, p, q4);
  }
  __syncthreads();  // everyone done reading input layout

  // ------- phase 3a: scatter output chunk A = out floats [0,5376) ------
#pragma unroll
  for (int k = 0; k < 3; ++k) lds[m * 3 + k] = r0[k];
  lds[768 + m] = o0;
#pragma unroll
  for (int i = 0; i < 3; ++i) lds[1024 + m * 3 + i] = o1[i];
#pragma unroll
  for (int i = 0; i < 5; ++i) lds[1792 + m * 5 + i] = o2[i];
  lds[3072 + m] = q0;
#pragma unroll
  for (int i = 0; i < 3; ++i) lds[3328 + m * 3 + i] = q1[i];
#pragma unroll
  for (int i = 0; i < 5; ++i) lds[4096 + m * 5 + i] = q2[i];
  __syncthreads();

  // ------- phase 4a: coalesced store chunk A (1344 float4) -------------
  {
    const float4* l4 = reinterpret_cast<const float4*>(lds);
    float4* dst = reinterpret_cast<float4*>(out + (size_t)b * 9472);
#pragma unroll
    for (int k = 0; k < 5; ++k) dst[t + k * 256] = l4[t + k * 256];  // 1280
    if (t < 64) dst[1280 + t] = l4[1280 + t];                         // 1344
  }
  __syncthreads();  // chunk A fully read before overwrite

  // ------- phase 3b: scatter chunk B = out floats [5376,9472) ----------
#pragma unroll
  for (int i = 0; i < 7; ++i) lds[m * 7 + i] = q3[i];         // 0..1792
#pragma unroll
  for (int i = 0; i < 9; ++i) lds[1792 + m * 9 + i] = q4[i];  // 1792..4096
  __syncthreads();

  // ------- phase 4b: coalesced store chunk B (1024 float4) -------------
  {
    const float4* l4 = reinterpret_cast<const float4*>(lds);
    float4* dst = reinterpret_cast<float4*>(out + (size_t)b * 9472 + 5376);
#pragma unroll
    for (int k = 0; k < 4; ++k) dst[t + k * 256] = l4[t + k * 256];  // 1024
  }
}

extern "C" void kernel_launch(void* const* d_in, const int* in_sizes, int n_in,
                              void* d_out, int out_size, void* d_ws, size_t ws_size,
                              hipStream_t stream) {
  const float* f1 = (const float*)d_in[0];
  const float* f2 = (const float*)d_in[1];
  float* out = (float*)d_out;
  const int B = in_sizes[0] / 2304;  // 8192
  tp_kernel<<<B, 256, 0, stream>>>(f1, f2, out, B);
}

// Round 6
// 96.898 us; speedup vs baseline: 1.0031x; 1.0031x over previous
//
#include <hip/hip_runtime.h>

// ---------------------------------------------------------------------------
// Compile-time Clebsch-Gordan / real Wigner-3j machinery (mirrors reference).
// ---------------------------------------------------------------------------
namespace cg {

constexpr double fact(int n) {
  double r = 1.0;
  for (int i = 2; i <= n; ++i) r *= (double)i;
  return r;
}

constexpr double csqrt(double x) {
  if (x <= 0.0) return 0.0;
  double g = x < 1.0 ? 1.0 : x;
  for (int i = 0; i < 80; ++i) g = 0.5 * (g + x / g);
  return g;
}

struct cplx { double re, im; };
constexpr cplx cmul(cplx a, cplx b) {
  return cplx{a.re * b.re - a.im * b.im, a.re * b.im + a.im * b.re};
}

// Racah formula, e3nn convention: <j1 m1 j2 m2 | j3 m3>
constexpr double su2_cg(int j1, int m1, int j2, int m2, int j3, int m3) {
  if (m3 != m1 + m2) return 0.0;
  int vmin = -j1 + j2 + m3;
  if (-j1 + m1 > vmin) vmin = -j1 + m1;
  if (0 > vmin) vmin = 0;
  int vmax = j2 + j3 + m1;
  if (j3 - j1 + j2 < vmax) vmax = j3 - j1 + j2;
  if (j3 + m3 < vmax) vmax = j3 + m3;
  const double C = csqrt((2.0 * j3 + 1.0)
      * fact(j3 + j1 - j2) * fact(j3 - j1 + j2) * fact(j1 + j2 - j3)
      * fact(j3 + m3) * fact(j3 - m3)
      / (fact(j1 + j2 + j3 + 1) * fact(j1 - m1) * fact(j1 + m1)
         * fact(j2 - m2) * fact(j2 + m2)));
  double S = 0.0;
  for (int v = vmin; v <= vmax; ++v) {
    const double sgn = ((v + j2 + m2) & 1) ? -1.0 : 1.0;
    S += sgn * (fact(j2 + j3 + m1 - v) * fact(j1 - m1 + v)
         / (fact(v) * fact(j3 - j1 + j2 - v) * fact(j3 + m3 - v)
            * fact(v + j1 - j2 - m3)));
  }
  return C * S;
}

template <int L> struct QMat { cplx q[2 * L + 1][2 * L + 1]; };

// real -> complex SH change of basis (e3nn convention), rows m', cols m
template <int L>
constexpr QMat<L> make_q() {
  QMat<L> Q{};
  const double s = 1.0 / csqrt(2.0);
  for (int m = -L; m < 0; ++m) {
    Q.q[L + m][L - m] = cplx{s, 0.0};
    Q.q[L + m][L + m] = cplx{0.0, -s};
  }
  Q.q[L][L] = cplx{1.0, 0.0};
  for (int m = 1; m <= L; ++m) {
    const double sg = (m & 1) ? -1.0 : 1.0;
    Q.q[L + m][L + m] = cplx{sg * s, 0.0};
    Q.q[L + m][L - m] = cplx{0.0, sg * s};
  }
  cplx p{1.0, 0.0};                        // (-i)^L prefactor
  for (int t = 0; t < L; ++t) p = cmul(p, cplx{0.0, -1.0});
  for (int r = 0; r < 2 * L + 1; ++r)
    for (int c = 0; c < 2 * L + 1; ++c)
      Q.q[r][c] = cmul(p, Q.q[r][c]);
  return Q;
}

template <int L, int L1, int L2>
struct W3 { float t[2 * L + 1][2 * L1 + 1][2 * L2 + 1]; };

// real-basis wigner3j(L, L1, L2) * sqrt(2L+1), exactly as the reference CG dict
template <int L, int L1, int L2>
constexpr W3<L, L1, L2> wigner() {
  const QMat<L>  Q1 = make_q<L>();
  const QMat<L1> Q2 = make_q<L1>();
  const QMat<L2> Q3 = make_q<L2>();
  double C[2 * L + 1][2 * L1 + 1][2 * L2 + 1] = {};
  for (int m1 = -L; m1 <= L; ++m1)
    for (int m2 = -L1; m2 <= L1; ++m2) {
      const int m3 = m1 + m2;
      if (m3 >= -L2 && m3 <= L2)
        C[L + m1][L1 + m2][L2 + m3] = su2_cg(L, m1, L1, m2, L2, m3);
    }
  const double scale = csqrt(2.0 * L + 1.0) / csqrt(2.0 * L2 + 1.0);
  W3<L, L1, L2> R{};
  for (int j = 0; j < 2 * L + 1; ++j)
    for (int l = 0; l < 2 * L1 + 1; ++l)
      for (int m = 0; m < 2 * L2 + 1; ++m) {
        cplx acc{0.0, 0.0};
        for (int i = 0; i < 2 * L + 1; ++i) {
          const cplx q1 = Q1.q[i][j];
          if (q1.re == 0.0 && q1.im == 0.0) continue;
          for (int k = 0; k < 2 * L1 + 1; ++k) {
            const cplx q2 = Q2.q[k][l];
            if (q2.re == 0.0 && q2.im == 0.0) continue;
            const cplx q12 = cmul(q1, q2);
            for (int n = 0; n < 2 * L2 + 1; ++n) {
              const double c = C[i][k][n];
              if (c == 0.0) continue;
              const cplx q3c{Q3.q[n][m].re, -Q3.q[n][m].im};  // conj
              const cplx term = cmul(q12, q3c);
              acc.re += term.re * c;
              acc.im += term.im * c;
            }
          }
        }
        R.t[j][l][m] = (float)(acc.re * scale);
      }
  return R;
}

constexpr W3<0, 1, 1> W011 = wigner<0, 1, 1>();
constexpr W3<1, 1, 1> W111 = wigner<1, 1, 1>();
constexpr W3<2, 1, 1> W211 = wigner<2, 1, 1>();
constexpr W3<0, 2, 2> W022 = wigner<0, 2, 2>();
constexpr W3<1, 2, 2> W122 = wigner<1, 2, 2>();
constexpr W3<2, 2, 2> W222 = wigner<2, 2, 2>();
constexpr W3<3, 2, 2> W322 = wigner<3, 2, 2>();
constexpr W3<4, 2, 2> W422 = wigner<4, 2, 2>();

}  // namespace cg

// ---------------------------------------------------------------------------
// Kernel
// ---------------------------------------------------------------------------

template <int L, int L1, int L2>
__device__ __forceinline__ void contract(const cg::W3<L, L1, L2>& W,
                                         const float (&p)[2 * L1 + 1][2 * L2 + 1],
                                         float* __restrict__ o) {
#pragma unroll
  for (int i = 0; i < 2 * L + 1; ++i) {
    float acc = 0.0f;
#pragma unroll
    for (int j = 0; j < 2 * L1 + 1; ++j)
#pragma unroll
      for (int k = 0; k < 2 * L2 + 1; ++k) {
        const float c = W.t[i][j][k];
        if (c != 0.0f) acc = __builtin_fmaf(c, p[j][k], acc);
      }
    o[i] = acc;
  }
}

// ONE WAVE PER BLOCK (64 threads). Block bid handles channels
// [64w, 64w+64) of row b, where b = bid>>2, w = bid&3. Every per-(pair,l)
// segment of f1/f2/out is channel-major contiguous, so this wave's slice of
// every segment is contiguous in global memory -> float4-coalesced staging
// both ways through a private 9.5 KB LDS buffer. __syncthreads() on a
// single-wave workgroup costs only the waitcnt (no sibling waves to stall
// on), giving the compiler/HW ordering that the barrier-free R4 lacked
// (cross-lane LDS RAW was reordered under per-thread alias analysis).
//
// LDS region: 2368 floats. input layout (first 1280):
//   f1l0 @0(64) | f1l1 @64(192) | f1l2 @256(320)
//   f2a @576(192) | f2b @768(192) | f2c @960(320)
// output layout (all 2368):
//   p0 @0(192) | p1l0 @192(64) | p1l1 @256(192) | p1l2 @448(320)
//   p2l0 @768(64) | p2l1 @832(192) | p2l2 @1024(320) | p2l3 @1344(448)
//   p2l4 @1792(576)
__global__ __launch_bounds__(64) void tp_kernel(
    const float* __restrict__ f1, const float* __restrict__ f2,
    float* __restrict__ out, int B) {
  __shared__ __align__(16) float Wr[2368];  // 9472 B
  const int bid = blockIdx.x;
  const int b = bid >> 2;
  if (b >= B) return;
  const int w = bid & 3;   // channel-chunk 0..3
  const int l = threadIdx.x;  // lane 0..63  (channel m = 64w + l)

  // ---------------- stage-in: contiguous f4 slices ----------------------
  {
    const float4* s1 = reinterpret_cast<const float4*>(f1 + (size_t)b * 2304);
    const float4* s2 = reinterpret_cast<const float4*>(f2 + (size_t)b * 2816);
    float4* L4 = reinterpret_cast<float4*>(Wr);
    if (l < 16) L4[l] = s1[16 * w + l];                         // f1 l0 (16)
    if (l < 48) L4[16 + l] = s1[64 + 48 * w + l];               // f1 l1 (48)
    L4[64 + l] = s1[256 + 80 * w + l];                          // f1 l2 (80)
    if (l < 16) L4[128 + l] = s1[256 + 80 * w + 64 + l];
    if (l < 48) L4[144 + l] = s2[48 * w + l];                   // f2 a (48)
    if (l < 48) L4[192 + l] = s2[192 + 48 * w + l];             // f2 b (48)
    L4[240 + l] = s2[384 + 80 * w + l];                         // f2 c (80)
    if (l < 16) L4[304 + l] = s2[384 + 80 * w + 64 + l];
  }
  __syncthreads();  // single-wave: just a waitcnt + ordering fence

  // ---------------- read inputs (all reads before any scatter) ----------
  const float s0 = Wr[l];
  float ca[3], a1[3], cb[3], a2[5], cc[5];
#pragma unroll
  for (int k = 0; k < 3; ++k) ca[k] = Wr[576 + l * 3 + k];
#pragma unroll
  for (int j = 0; j < 3; ++j) a1[j] = Wr[64 + l * 3 + j];
#pragma unroll
  for (int k = 0; k < 3; ++k) cb[k] = Wr[768 + l * 3 + k];
#pragma unroll
  for (int j = 0; j < 5; ++j) a2[j] = Wr[256 + l * 5 + j];
#pragma unroll
  for (int k = 0; k < 5; ++k) cc[k] = Wr[960 + l * 5 + k];

  // ---------------- compute (all outputs into registers) ----------------
  float r0[3];
#pragma unroll
  for (int k = 0; k < 3; ++k) r0[k] = s0 * ca[k];

  float o0, o1[3], o2[5];
  {
    float p[3][3];
#pragma unroll
    for (int j = 0; j < 3; ++j)
#pragma unroll
      for (int k = 0; k < 3; ++k) p[j][k] = a1[j] * cb[k];
    contract<0, 1, 1>(cg::W011, p, &o0);
    contract<1, 1, 1>(cg::W111, p, o1);
    contract<2, 1, 1>(cg::W211, p, o2);
  }
  float q0, q1[3], q2[5], q3[7], q4[9];
  {
    float p[5][5];
#pragma unroll
    for (int j = 0; j < 5; ++j)
#pragma unroll
      for (int k = 0; k < 5; ++k) p[j][k] = a2[j] * cc[k];
    contract<0, 2, 2>(cg::W022, p, &q0);
    contract<1, 2, 2>(cg::W122, p, q1);
    contract<2, 2, 2>(cg::W222, p, q2);
    contract<3, 2, 2>(cg::W322, p, q3);
    contract<4, 2, 2>(cg::W422, p, q4);
  }
  __syncthreads();  // all input reads done before overwrite

  // ---------------- scatter into LDS (output layout) --------------------
#pragma unroll
  for (int k = 0; k < 3; ++k) Wr[l * 3 + k] = r0[k];
  Wr[192 + l] = o0;
#pragma unroll
  for (int i = 0; i < 3; ++i) Wr[256 + l * 3 + i] = o1[i];
#pragma unroll
  for (int i = 0; i < 5; ++i) Wr[448 + l * 5 + i] = o2[i];
  Wr[768 + l] = q0;
#pragma unroll
  for (int i = 0; i < 3; ++i) Wr[832 + l * 3 + i] = q1[i];
#pragma unroll
  for (int i = 0; i < 5; ++i) Wr[1024 + l * 5 + i] = q2[i];
#pragma unroll
  for (int i = 0; i < 7; ++i) Wr[1344 + l * 7 + i] = q3[i];
#pragma unroll
  for (int i = 0; i < 9; ++i) Wr[1792 + l * 9 + i] = q4[i];
  __syncthreads();  // scatter visible before f4 readback

  // ---------------- store-out: contiguous f4 slices ---------------------
  {
    const float4* OF = reinterpret_cast<const float4*>(Wr);
    float4* D = reinterpret_cast<float4*>(out + (size_t)b * 9472);
    if (l < 48) D[48 * w + l] = OF[l];                           // p0   (48)
    if (l < 16) D[192 + 16 * w + l] = OF[48 + l];                // p1l0 (16)
    if (l < 48) D[256 + 48 * w + l] = OF[64 + l];                // p1l1 (48)
    D[448 + 80 * w + l] = OF[112 + l];                           // p1l2 (80)
    if (l < 16) D[448 + 80 * w + 64 + l] = OF[176 + l];
    if (l < 16) D[768 + 16 * w + l] = OF[192 + l];               // p2l0 (16)
    if (l < 48) D[832 + 48 * w + l] = OF[208 + l];               // p2l1 (48)
    D[1024 + 80 * w + l] = OF[256 + l];                          // p2l2 (80)
    if (l < 16) D[1024 + 80 * w + 64 + l] = OF[320 + l];
    D[1344 + 112 * w + l] = OF[336 + l];                         // p2l3 (112)
    if (l < 48) D[1344 + 112 * w + 64 + l] = OF[400 + l];
    D[1792 + 144 * w + l] = OF[448 + l];                         // p2l4 (144)
    D[1792 + 144 * w + 64 + l] = OF[512 + l];
    if (l < 16) D[1792 + 144 * w + 128 + l] = OF[576 + l];
  }
}

extern "C" void kernel_launch(void* const* d_in, const int* in_sizes, int n_in,
                              void* d_out, int out_size, void* d_ws, size_t ws_size,
                              hipStream_t stream) {
  const float* f1 = (const float*)d_in[0];
  const float* f2 = (const float*)d_in[1];
  float* out = (float*)d_out;
  const int B = in_sizes[0] / 2304;  // 8192
  tp_kernel<<<B * 4, 64, 0, stream>>>(f1, f2, out, B);
}

// Round 7
// 92.735 us; speedup vs baseline: 1.0481x; 1.0449x over previous
//
#include <hip/hip_runtime.h>

// ---------------------------------------------------------------------------
// Compile-time Clebsch-Gordan / real Wigner-3j machinery (mirrors reference).
// ---------------------------------------------------------------------------
namespace cg {

constexpr double fact(int n) {
  double r = 1.0;
  for (int i = 2; i <= n; ++i) r *= (double)i;
  return r;
}

constexpr double csqrt(double x) {
  if (x <= 0.0) return 0.0;
  double g = x < 1.0 ? 1.0 : x;
  for (int i = 0; i < 80; ++i) g = 0.5 * (g + x / g);
  return g;
}

struct cplx { double re, im; };
constexpr cplx cmul(cplx a, cplx b) {
  return cplx{a.re * b.re - a.im * b.im, a.re * b.im + a.im * b.re};
}

// Racah formula, e3nn convention: <j1 m1 j2 m2 | j3 m3>
constexpr double su2_cg(int j1, int m1, int j2, int m2, int j3, int m3) {
  if (m3 != m1 + m2) return 0.0;
  int vmin = -j1 + j2 + m3;
  if (-j1 + m1 > vmin) vmin = -j1 + m1;
  if (0 > vmin) vmin = 0;
  int vmax = j2 + j3 + m1;
  if (j3 - j1 + j2 < vmax) vmax = j3 - j1 + j2;
  if (j3 + m3 < vmax) vmax = j3 + m3;
  const double C = csqrt((2.0 * j3 + 1.0)
      * fact(j3 + j1 - j2) * fact(j3 - j1 + j2) * fact(j1 + j2 - j3)
      * fact(j3 + m3) * fact(j3 - m3)
      / (fact(j1 + j2 + j3 + 1) * fact(j1 - m1) * fact(j1 + m1)
         * fact(j2 - m2) * fact(j2 + m2)));
  double S = 0.0;
  for (int v = vmin; v <= vmax; ++v) {
    const double sgn = ((v + j2 + m2) & 1) ? -1.0 : 1.0;
    S += sgn * (fact(j2 + j3 + m1 - v) * fact(j1 - m1 + v)
         / (fact(v) * fact(j3 - j1 + j2 - v) * fact(j3 + m3 - v)
            * fact(v + j1 - j2 - m3)));
  }
  return C * S;
}

template <int L> struct QMat { cplx q[2 * L + 1][2 * L + 1]; };

// real -> complex SH change of basis (e3nn convention), rows m', cols m
template <int L>
constexpr QMat<L> make_q() {
  QMat<L> Q{};
  const double s = 1.0 / csqrt(2.0);
  for (int m = -L; m < 0; ++m) {
    Q.q[L + m][L - m] = cplx{s, 0.0};
    Q.q[L + m][L + m] = cplx{0.0, -s};
  }
  Q.q[L][L] = cplx{1.0, 0.0};
  for (int m = 1; m <= L; ++m) {
    const double sg = (m & 1) ? -1.0 : 1.0;
    Q.q[L + m][L + m] = cplx{sg * s, 0.0};
    Q.q[L + m][L - m] = cplx{0.0, sg * s};
  }
  cplx p{1.0, 0.0};                        // (-i)^L prefactor
  for (int t = 0; t < L; ++t) p = cmul(p, cplx{0.0, -1.0});
  for (int r = 0; r < 2 * L + 1; ++r)
    for (int c = 0; c < 2 * L + 1; ++c)
      Q.q[r][c] = cmul(p, Q.q[r][c]);
  return Q;
}

template <int L, int L1, int L2>
struct W3 { float t[2 * L + 1][2 * L1 + 1][2 * L2 + 1]; };

// real-basis wigner3j(L, L1, L2) * sqrt(2L+1), exactly as the reference CG dict
template <int L, int L1, int L2>
constexpr W3<L, L1, L2> wigner() {
  const QMat<L>  Q1 = make_q<L>();
  const QMat<L1> Q2 = make_q<L1>();
  const QMat<L2> Q3 = make_q<L2>();
  double C[2 * L + 1][2 * L1 + 1][2 * L2 + 1] = {};
  for (int m1 = -L; m1 <= L; ++m1)
    for (int m2 = -L1; m2 <= L1; ++m2) {
      const int m3 = m1 + m2;
      if (m3 >= -L2 && m3 <= L2)
        C[L + m1][L1 + m2][L2 + m3] = su2_cg(L, m1, L1, m2, L2, m3);
    }
  const double scale = csqrt(2.0 * L + 1.0) / csqrt(2.0 * L2 + 1.0);
  W3<L, L1, L2> R{};
  for (int j = 0; j < 2 * L + 1; ++j)
    for (int l = 0; l < 2 * L1 + 1; ++l)
      for (int m = 0; m < 2 * L2 + 1; ++m) {
        cplx acc{0.0, 0.0};
        for (int i = 0; i < 2 * L + 1; ++i) {
          const cplx q1 = Q1.q[i][j];
          if (q1.re == 0.0 && q1.im == 0.0) continue;
          for (int k = 0; k < 2 * L1 + 1; ++k) {
            const cplx q2 = Q2.q[k][l];
            if (q2.re == 0.0 && q2.im == 0.0) continue;
            const cplx q12 = cmul(q1, q2);
            for (int n = 0; n < 2 * L2 + 1; ++n) {
              const double c = C[i][k][n];
              if (c == 0.0) continue;
              const cplx q3c{Q3.q[n][m].re, -Q3.q[n][m].im};  // conj
              const cplx term = cmul(q12, q3c);
              acc.re += term.re * c;
              acc.im += term.im * c;
            }
          }
        }
        R.t[j][l][m] = (float)(acc.re * scale);
      }
  return R;
}

constexpr W3<0, 1, 1> W011 = wigner<0, 1, 1>();
constexpr W3<1, 1, 1> W111 = wigner<1, 1, 1>();
constexpr W3<2, 1, 1> W211 = wigner<2, 1, 1>();
constexpr W3<0, 2, 2> W022 = wigner<0, 2, 2>();
constexpr W3<1, 2, 2> W122 = wigner<1, 2, 2>();
constexpr W3<2, 2, 2> W222 = wigner<2, 2, 2>();
constexpr W3<3, 2, 2> W322 = wigner<3, 2, 2>();
constexpr W3<4, 2, 2> W422 = wigner<4, 2, 2>();

}  // namespace cg

// ---------------------------------------------------------------------------
// Kernel
// ---------------------------------------------------------------------------

template <int L, int L1, int L2>
__device__ __forceinline__ void contract(const cg::W3<L, L1, L2>& W,
                                         const float (&p)[2 * L1 + 1][2 * L2 + 1],
                                         float* __restrict__ o) {
#pragma unroll
  for (int i = 0; i < 2 * L + 1; ++i) {
    float acc = 0.0f;
#pragma unroll
    for (int j = 0; j < 2 * L1 + 1; ++j)
#pragma unroll
      for (int k = 0; k < 2 * L2 + 1; ++k) {
        const float c = W.t[i][j][k];
        if (c != 0.0f) acc = __builtin_fmaf(c, p[j][k], acc);
      }
    o[i] = acc;
  }
}

// HYBRID version (best-of R0/R2 per A/B history):
//  - INPUT: direct per-lane global loads. Per lane they are 12-20 B
//    contiguous (coalescing sweet spot); every cache line is fully covered
//    within each wave's instruction, so no over-fetch. No input LDS staging,
//    no pre-compute barrier; load latency overlaps compute across 16 waves/CU.
//  - OUTPUT: full-row staging through LDS (output layout), ONE barrier, then
//    float4-coalesced stores (strided scalar stores cost ~1.4x line
//    transactions -> staging the 310 MB write side is where LDS pays).
// All LDS scatter strides are odd => <=2-way bank aliasing (free on CDNA4).
__global__ __launch_bounds__(256) void tp_kernel(
    const float* __restrict__ f1, const float* __restrict__ f2,
    float* __restrict__ out, int B) {
  __shared__ __align__(16) float lds[9472];  // 37888 B -> 4 blocks/CU
  const int b = blockIdx.x;
  if (b >= B) return;
  const int m = threadIdx.x;  // channel 0..255
  const float* F1 = f1 + (size_t)b * 2304;
  const float* F2 = f2 + (size_t)b * 2816;

  // ---------------- direct input loads (contiguous per lane) -----------
  const float s0 = F1[m];
  float a1[3], a2[5], ca[3], cb[3], cc[5];
#pragma unroll
  for (int j = 0; j < 3; ++j) a1[j] = F1[256 + m * 3 + j];
#pragma unroll
  for (int j = 0; j < 5; ++j) a2[j] = F1[1024 + m * 5 + j];
#pragma unroll
  for (int k = 0; k < 3; ++k) ca[k] = F2[m * 3 + k];
#pragma unroll
  for (int k = 0; k < 3; ++k) cb[k] = F2[768 + m * 3 + k];
#pragma unroll
  for (int k = 0; k < 5; ++k) cc[k] = F2[1536 + m * 5 + k];

  // ---------------- compute (all outputs into registers) ----------------
  float r0[3];
#pragma unroll
  for (int k = 0; k < 3; ++k) r0[k] = s0 * ca[k];

  float o0, o1[3], o2[5];
  {
    float p[3][3];
#pragma unroll
    for (int j = 0; j < 3; ++j)
#pragma unroll
      for (int k = 0; k < 3; ++k) p[j][k] = a1[j] * cb[k];
    contract<0, 1, 1>(cg::W011, p, &o0);
    contract<1, 1, 1>(cg::W111, p, o1);
    contract<2, 1, 1>(cg::W211, p, o2);
  }
  float q0, q1[3], q2[5], q3[7], q4[9];
  {
    float p[5][5];
#pragma unroll
    for (int j = 0; j < 5; ++j)
#pragma unroll
      for (int k = 0; k < 5; ++k) p[j][k] = a2[j] * cc[k];
    contract<0, 2, 2>(cg::W022, p, &q0);
    contract<1, 2, 2>(cg::W122, p, q1);
    contract<2, 2, 2>(cg::W222, p, q2);
    contract<3, 2, 2>(cg::W322, p, q3);
    contract<4, 2, 2>(cg::W422, p, q4);
  }

  // ---------------- scatter outputs into LDS (output layout) ------------
#pragma unroll
  for (int k = 0; k < 3; ++k) lds[m * 3 + k] = r0[k];
  lds[768 + m] = o0;
#pragma unroll
  for (int i = 0; i < 3; ++i) lds[1024 + m * 3 + i] = o1[i];
#pragma unroll
  for (int i = 0; i < 5; ++i) lds[1792 + m * 5 + i] = o2[i];
  lds[3072 + m] = q0;
#pragma unroll
  for (int i = 0; i < 3; ++i) lds[3328 + m * 3 + i] = q1[i];
#pragma unroll
  for (int i = 0; i < 5; ++i) lds[4096 + m * 5 + i] = q2[i];
#pragma unroll
  for (int i = 0; i < 7; ++i) lds[5376 + m * 7 + i] = q3[i];
#pragma unroll
  for (int i = 0; i < 9; ++i) lds[7168 + m * 9 + i] = q4[i];
  __syncthreads();  // the ONLY barrier

  // ---------------- coalesced float4 stage-out --------------------------
  {
    const float4* l4 = reinterpret_cast<const float4*>(lds);
    float4* dst = reinterpret_cast<float4*>(out + (size_t)b * 9472);
#pragma unroll
    for (int k = 0; k < 9; ++k) dst[m + k * 256] = l4[m + k * 256];  // 2304
    if (m < 64) dst[2304 + m] = l4[2304 + m];                         // 2368
  }
}

extern "C" void kernel_launch(void* const* d_in, const int* in_sizes, int n_in,
                              void* d_out, int out_size, void* d_ws, size_t ws_size,
                              hipStream_t stream) {
  const float* f1 = (const float*)d_in[0];
  const float* f2 = (const float*)d_in[1];
  float* out = (float*)d_out;
  const int B = in_sizes[0] / 2304;  // 8192
  tp_kernel<<<B, 256, 0, stream>>>(f1, f2, out, B);
}